// Round 1
// baseline (2347.522 us; speedup 1.0000x reference)
//
#include <hip/hip_runtime.h>

// SimpleSelfAttention: B=128, S=D=512, fp32.
// Per batch b (X = x[b], 512x512):
//   Qt = Wq * X^T + bq (row-bias)        [Qt[e,s] = Q[s,e]]
//   K  = X * Wk^T + bk, V = X * Wv^T + bv
//   E[i,j] = sum_k Qt[i,k]*K[j,k]        (= energy)
//   A = row-softmax(E)
//   Out[s,i] = sum_j V[s,j]*A[i,j]
// Every matmul is the same NT GEMM: C[m,n] = sum_k A[m,k]*B[n,k].

#define NDIM 512
#define NBATCH 128
constexpr long SD = (long)NDIM * NDIM;   // elements per 512x512 matrix

// ---------------- NT GEMM, fp32, 64x64 tile, BK=16, 256 threads, 4x4/thread --
template<bool HAS_BIAS, bool BIAS_ROW>
__global__ __launch_bounds__(256) void gemm_nt(
    const float* __restrict__ A, long sA,
    const float* __restrict__ Bm, long sB,
    float* __restrict__ C, long sC,
    const float* __restrict__ bias)
{
    constexpr int BM = 64, BN = 64, BK = 16;
    __shared__ float As[BK][BM + 4];   // row length 68 keeps float4 alignment
    __shared__ float Bs[BK][BN + 4];

    const int z = blockIdx.z;
    const float* Ab = A  + (long)z * sA;
    const float* Bb = Bm + (long)z * sB;
    float*       Cb = C  + (long)z * sC;

    const int m0 = blockIdx.y * BM;
    const int n0 = blockIdx.x * BN;
    const int tx = threadIdx.x, ty = threadIdx.y;   // 16x16
    const int tid = ty * 16 + tx;
    const int lr = tid >> 2;   // 0..63: row within tile for staging loads
    const int lq = tid & 3;    // quad along k

    float acc[4][4] = {};

    for (int k0 = 0; k0 < NDIM; k0 += BK) {
        const float4 av = *(const float4*)(Ab + (long)(m0 + lr) * NDIM + k0 + lq * 4);
        const float4 bv = *(const float4*)(Bb + (long)(n0 + lr) * NDIM + k0 + lq * 4);
        __syncthreads();   // WAR: previous iter's LDS reads done
        As[lq * 4 + 0][lr] = av.x; As[lq * 4 + 1][lr] = av.y;
        As[lq * 4 + 2][lr] = av.z; As[lq * 4 + 3][lr] = av.w;
        Bs[lq * 4 + 0][lr] = bv.x; Bs[lq * 4 + 1][lr] = bv.y;
        Bs[lq * 4 + 2][lr] = bv.z; Bs[lq * 4 + 3][lr] = bv.w;
        __syncthreads();   // RAW: tile staged
        #pragma unroll
        for (int kk = 0; kk < BK; ++kk) {
            const float4 a = *(const float4*)&As[kk][ty * 4];
            const float4 b = *(const float4*)&Bs[kk][tx * 4];
            const float ar[4] = {a.x, a.y, a.z, a.w};
            const float br[4] = {b.x, b.y, b.z, b.w};
            #pragma unroll
            for (int i = 0; i < 4; ++i)
                #pragma unroll
                for (int j = 0; j < 4; ++j)
                    acc[i][j] = fmaf(ar[i], br[j], acc[i][j]);
        }
    }

    #pragma unroll
    for (int i = 0; i < 4; ++i) {
        const int m = m0 + ty * 4 + i;
        float vals[4];
        #pragma unroll
        for (int j = 0; j < 4; ++j) {
            float v = acc[i][j];
            if (HAS_BIAS) v += BIAS_ROW ? bias[m] : bias[n0 + tx * 4 + j];
            vals[j] = v;
        }
        *(float4*)(Cb + (long)m * NDIM + n0 + tx * 4) =
            make_float4(vals[0], vals[1], vals[2], vals[3]);
    }
}

// ---------------- row softmax, one block (256 thr) per 512-elem row, in-place
__global__ __launch_bounds__(256) void softmax_rows(float* __restrict__ E)
{
    __shared__ float red[256];
    float* p = E + (size_t)blockIdx.x * NDIM;
    const int t = threadIdx.x;

    float2 v = *(float2*)(p + 2 * t);
    red[t] = fmaxf(v.x, v.y);
    __syncthreads();
    for (int s = 128; s > 0; s >>= 1) {
        if (t < s) red[t] = fmaxf(red[t], red[t + s]);
        __syncthreads();
    }
    const float mx = red[0];
    __syncthreads();

    float2 e;
    e.x = expf(v.x - mx);
    e.y = expf(v.y - mx);
    red[t] = e.x + e.y;
    __syncthreads();
    for (int s = 128; s > 0; s >>= 1) {
        if (t < s) red[t] += red[t + s];
        __syncthreads();
    }
    const float inv = 1.0f / red[0];
    e.x *= inv; e.y *= inv;
    *(float2*)(p + 2 * t) = e;
}

extern "C" void kernel_launch(void* const* d_in, const int* in_sizes, int n_in,
                              void* d_out, int out_size, void* d_ws, size_t ws_size,
                              hipStream_t stream)
{
    const float* x  = (const float*)d_in[0];
    const float* Wq = (const float*)d_in[1];
    const float* bq = (const float*)d_in[2];
    const float* Wk = (const float*)d_in[3];
    const float* bk = (const float*)d_in[4];
    const float* Wv = (const float*)d_in[5];
    const float* bv = (const float*)d_in[6];
    float* out = (float*)d_out;

    // Workspace: per in-flight batch we need Qt, K, V, E = 4 x 1 MiB.
    const size_t perBatch = 4ull * SD * sizeof(float);
    int c = (int)(ws_size / perBatch);
    if (c < 1)       c = 1;       // assume ws_size >= 4 MiB
    if (c > NBATCH)  c = NBATCH;

    float* Qt = (float*)d_ws;
    float* Kw = Qt + (size_t)c * SD;
    float* Vw = Kw + (size_t)c * SD;
    float* Ew = Vw + (size_t)c * SD;

    const dim3 blk(16, 16);
    for (int b0 = 0; b0 < NBATCH; b0 += c) {
        const int cb = (NBATCH - b0 < c) ? (NBATCH - b0) : c;
        const dim3 grid(NDIM / 64, NDIM / 64, cb);
        const float* xb = x + (size_t)b0 * SD;

        // Qt[e,s] = sum_d Wq[e,d]*x[s,d] + bq[e]   (bias on row)
        gemm_nt<true, true ><<<grid, blk, 0, stream>>>(Wq, 0,  xb, SD, Qt, SD, bq);
        // K[s,e] = sum_d x[s,d]*Wk[e,d] + bk[e]
        gemm_nt<true, false><<<grid, blk, 0, stream>>>(xb, SD, Wk, 0,  Kw, SD, bk);
        // V[s,e] = sum_d x[s,d]*Wv[e,d] + bv[e]
        gemm_nt<true, false><<<grid, blk, 0, stream>>>(xb, SD, Wv, 0,  Vw, SD, bv);
        // E[i,j] = sum_k Qt[i,k]*K[j,k]
        gemm_nt<false, false><<<grid, blk, 0, stream>>>(Qt, SD, Kw, SD, Ew, SD, nullptr);
        // A = row-softmax(E), in place
        softmax_rows<<<dim3(cb * NDIM), dim3(256), 0, stream>>>(Ew);
        // Out[s,i] = sum_j V[s,j]*A[i,j]
        gemm_nt<false, false><<<grid, blk, 0, stream>>>(Vw, SD, Ew, SD,
                                                        out + (size_t)b0 * SD, SD, nullptr);
    }
}

// Round 3
// 814.080 us; speedup vs baseline: 2.8836x; 2.8836x over previous
//
#include <hip/hip_runtime.h>
#include <hip/hip_bf16.h>

// SimpleSelfAttention, B=128, S=D=512, fp32 in/out, bf16 MFMA compute.
// Per batch (X = x[b]):
//   Qt[e,s] = sum_d Wq[e,d] X[s,d] + bq[e]     (split hi/lo 3-pass, split out)
//   K [s,e] = sum_d X[s,d] Wk[e,d] + bk[e]     (split hi/lo 3-pass, split out)
//   V [s,e] = sum_d X[s,d] Wv[e,d] + bv[e]     (1-pass bf16)
//   E[i,j]  = sum_k Qt[i,k] K[j,k]             (split 3-pass, fp32 out)
//             [reference contracts Qp's seq axis vs Kp's embed axis: B-op is
//              PLAIN K, not K^T — this was the Round-2 bug]
//   A = row-softmax(E)  (fp32 math, bf16 out)
//   Out[s,i] = sum_j V[s,j] A[i,j]             (1-pass, fp32 out)
// All matmuls are the same NT GEMM C[m,n] = sum_k A[m,k] B[n,k].

#define NDIM 512
#define NBATCH 128
constexpr size_t SD = (size_t)NDIM * NDIM;

typedef __attribute__((ext_vector_type(8))) short bf16x8;   // 8 bf16 = 4 VGPR
typedef __attribute__((ext_vector_type(4))) float f32x4;

typedef const __attribute__((address_space(1))) unsigned int* gas_ptr;
typedef __attribute__((address_space(3))) unsigned int* las_ptr;

struct alignas(8) us4 { unsigned short x, y, z, w; };
struct alignas(4) us2 { unsigned short x, y; };

__device__ __forceinline__ void gl_lds16(const void* g, void* lds) {
    // async global->LDS, 16B per lane; HW dest = wave-uniform base + lane*16
    __builtin_amdgcn_global_load_lds((gas_ptr)g, (las_ptr)lds, 16, 0, 0);
}

__device__ __forceinline__ unsigned short f2bf(float x) {
    return __builtin_bit_cast(unsigned short, __float2bfloat16(x));
}
__device__ __forceinline__ float bf2f(unsigned short u) {
    return __bfloat162float(__builtin_bit_cast(__hip_bfloat16, u));
}

// ---------------------------------------------------------------------------
// NT bf16 GEMM: C[m,n] = sum_seg sum_k Aseg[m,k]*Bseg[n,k]
// 128x128 tile, BK=64, 256 threads = 4 waves (2x2, each wave 64x64).
// EPI: 0 = fp32 store, 1 = bf16 store, 2 = bf16 hi/lo pair store
// BIAS: 0 = none, 1 = bias[m], 2 = bias[n]
template<int NSEG, int EPI, int BIAS>
__global__ __launch_bounds__(256) void gemm_bf16_nt(
    const unsigned short* a0, const unsigned short* a1, const unsigned short* a2, long sA,
    const unsigned short* b0, const unsigned short* b1, const unsigned short* b2, long sB,
    void* c0v, void* c1v, long sC, const float* __restrict__ bias)
{
    __shared__ unsigned short As[128 * 64];   // [m][k] row-major
    __shared__ unsigned short Bs[128 * 64];   // [n][k] row-major

    const int z  = blockIdx.z;
    const int m0 = blockIdx.y * 128, n0 = blockIdx.x * 128;
    const int tid = threadIdx.x;
    const int l = tid & 63, w = tid >> 6;
    const int wr = w >> 1, wc = w & 1;        // wave -> 64x64 quadrant

    // staging: thread tid loads 16B chunk (row = tid/8 + i*32, kcol = (tid%8)*8)
    const int srow = tid >> 3;
    const int scol = (tid & 7) << 3;
    unsigned short* ldsA = &As[tid * 8];      // *2B = tid*16 bytes, linear
    unsigned short* ldsB = &Bs[tid * 8];

    f32x4 acc[4][4] = {};

    const unsigned short* Asegs[3] = {a0, a1, a2};
    const unsigned short* Bsegs[3] = {b0, b1, b2};

    #pragma unroll
    for (int s = 0; s < NSEG; ++s) {
        const unsigned short* Ab = Asegs[s] + (size_t)z * sA + (size_t)m0 * NDIM;
        const unsigned short* Bb = Bsegs[s] + (size_t)z * sB + (size_t)n0 * NDIM;
        for (int k0 = 0; k0 < NDIM; k0 += 64) {
            __syncthreads();   // WAR: everyone done reading previous tile
            #pragma unroll
            for (int i = 0; i < 4; ++i) {
                gl_lds16(Ab + (size_t)(srow + i * 32) * NDIM + k0 + scol, ldsA + i * 2048);
                gl_lds16(Bb + (size_t)(srow + i * 32) * NDIM + k0 + scol, ldsB + i * 2048);
            }
            __syncthreads();   // RAW: barrier drains vmcnt -> tile visible
            #pragma unroll
            for (int kk = 0; kk < 2; ++kk) {
                bf16x8 af[4], bfv[4];
                #pragma unroll
                for (int f = 0; f < 4; ++f) {
                    af[f]  = *(const bf16x8*)&As[(wr * 64 + f * 16 + (l & 15)) * 64 + kk * 32 + (l >> 4) * 8];
                    bfv[f] = *(const bf16x8*)&Bs[(wc * 64 + f * 16 + (l & 15)) * 64 + kk * 32 + (l >> 4) * 8];
                }
                #pragma unroll
                for (int mi = 0; mi < 4; ++mi)
                    #pragma unroll
                    for (int ni = 0; ni < 4; ++ni)
                        acc[mi][ni] = __builtin_amdgcn_mfma_f32_16x16x32_bf16(
                            af[mi], bfv[ni], acc[mi][ni], 0, 0, 0);
            }
        }
    }

    // epilogue: C/D layout col = lane&15, row = (lane>>4)*4 + reg
    const size_t zc = (size_t)z * sC;
    const int cr = (l >> 4) << 2;
    const int cc = l & 15;
    #pragma unroll
    for (int mi = 0; mi < 4; ++mi) {
        #pragma unroll
        for (int r = 0; r < 4; ++r) {
            const int m = m0 + wr * 64 + mi * 16 + cr + r;
            const float bm = (BIAS == 1) ? bias[m] : 0.0f;
            #pragma unroll
            for (int ni = 0; ni < 4; ++ni) {
                const int n = n0 + wc * 64 + ni * 16 + cc;
                float v = acc[mi][ni][r] + bm + ((BIAS == 2) ? bias[n] : 0.0f);
                const size_t idx = zc + (size_t)m * NDIM + n;
                if (EPI == 0) {
                    ((float*)c0v)[idx] = v;
                } else if (EPI == 1) {
                    ((unsigned short*)c0v)[idx] = f2bf(v);
                } else {
                    const unsigned short h = f2bf(v);
                    ((unsigned short*)c0v)[idx] = h;
                    ((unsigned short*)c1v)[idx] = f2bf(v - bf2f(h));
                }
            }
        }
    }
}

// ---------------------------------------------------------------------------
// row softmax: fp32 in, bf16 out; one 256-thread block per 512-elem row
__global__ __launch_bounds__(256) void softmax_bf16(
    const float* __restrict__ E, unsigned short* __restrict__ A)
{
    __shared__ float red[256];
    const float* p = E + (size_t)blockIdx.x * NDIM;
    unsigned short* q = A + (size_t)blockIdx.x * NDIM;
    const int t = threadIdx.x;

    const float2 v = *(const float2*)(p + 2 * t);
    red[t] = fmaxf(v.x, v.y);
    __syncthreads();
    for (int s = 128; s > 0; s >>= 1) {
        if (t < s) red[t] = fmaxf(red[t], red[t + s]);
        __syncthreads();
    }
    const float mx = red[0];
    __syncthreads();

    const float ex = __expf(v.x - mx), ey = __expf(v.y - mx);
    red[t] = ex + ey;
    __syncthreads();
    for (int s = 128; s > 0; s >>= 1) {
        if (t < s) red[t] += red[t + s];
        __syncthreads();
    }
    const float inv = 1.0f / red[0];
    us2 o; o.x = f2bf(ex * inv); o.y = f2bf(ey * inv);
    *(us2*)(q + 2 * t) = o;
}

// ---------------------------------------------------------------------------
// fp32 -> bf16 hi (+ optional lo = bf16(v - hi)), float4-vectorized
template<bool LO>
__global__ __launch_bounds__(256) void split_to_bf16(
    const float* __restrict__ src,
    unsigned short* __restrict__ hi, unsigned short* __restrict__ lo, int n4)
{
    const int i = blockIdx.x * 256 + threadIdx.x;
    if (i >= n4) return;
    const float4 v = ((const float4*)src)[i];
    us4 h;
    h.x = f2bf(v.x); h.y = f2bf(v.y); h.z = f2bf(v.z); h.w = f2bf(v.w);
    ((us4*)hi)[i] = h;
    if (LO) {
        us4 g;
        g.x = f2bf(v.x - bf2f(h.x)); g.y = f2bf(v.y - bf2f(h.y));
        g.z = f2bf(v.z - bf2f(h.z)); g.w = f2bf(v.w - bf2f(h.w));
        ((us4*)lo)[i] = g;
    }
}

// ---------------------------------------------------------------------------
extern "C" void kernel_launch(void* const* d_in, const int* in_sizes, int n_in,
                              void* d_out, int out_size, void* d_ws, size_t ws_size,
                              hipStream_t stream)
{
    const float* x  = (const float*)d_in[0];
    const float* Wq = (const float*)d_in[1];
    const float* bq = (const float*)d_in[2];
    const float* Wk = (const float*)d_in[3];
    const float* bk = (const float*)d_in[4];
    const float* Wv = (const float*)d_in[5];
    const float* bv = (const float*)d_in[6];
    float* out = (float*)d_out;

    // ws budget in u16-units of SD: 6 weight units + 10*c per-chunk units
    // (xH,xL,QH,QL,KH,KL,V,A = 8 u16 + E fp32 = 2 u16-equiv)
    long cl = (long)(ws_size / (2 * SD));
    cl = (cl - 6) / 10;
    int c = (int)cl;
    if (c < 1) c = 1;
    if (c > 32) c = 32;
    while (128 % c) --c;   // uniform chunks: 32,16,8,...

    unsigned short* p = (unsigned short*)d_ws;
    auto take = [&](size_t elems) { unsigned short* r = p; p += elems; return r; };
    unsigned short* WqH = take(SD);
    unsigned short* WqL = take(SD);
    unsigned short* WkH = take(SD);
    unsigned short* WkL = take(SD);
    unsigned short* WvH = take(SD);
    unsigned short* xH  = take((size_t)c * SD);
    unsigned short* xL  = take((size_t)c * SD);
    unsigned short* QH  = take((size_t)c * SD);
    unsigned short* QL  = take((size_t)c * SD);
    unsigned short* KH  = take((size_t)c * SD);
    unsigned short* KL  = take((size_t)c * SD);
    unsigned short* Vb  = take((size_t)c * SD);
    unsigned short* Ab  = take((size_t)c * SD);
    float* Ew = (float*)p;   // c*SD fp32

    const int n4w = (int)(SD / 4);
    split_to_bf16<true ><<<dim3((n4w + 255) / 256), dim3(256), 0, stream>>>(Wq, WqH, WqL, n4w);
    split_to_bf16<true ><<<dim3((n4w + 255) / 256), dim3(256), 0, stream>>>(Wk, WkH, WkL, n4w);
    split_to_bf16<false><<<dim3((n4w + 255) / 256), dim3(256), 0, stream>>>(Wv, WvH, nullptr, n4w);

    for (int b0 = 0; b0 < NBATCH; b0 += c) {
        const int cb = (NBATCH - b0 < c) ? (NBATCH - b0) : c;
        const int n4 = (int)((size_t)cb * SD / 4);
        split_to_bf16<true><<<dim3((n4 + 255) / 256), dim3(256), 0, stream>>>(
            x + (size_t)b0 * SD, xH, xL, n4);

        const dim3 g(4, 4, cb), blk(256);
        // Qt = Wq*X^T + bq (row bias), split hi/lo out
        gemm_bf16_nt<3, 2, 1><<<g, blk, 0, stream>>>(
            WqH, WqL, WqH, 0,  xH, xH, xL, (long)SD,  QH, QL, (long)SD, bq);
        // K = X*Wv... K = X*Wk^T + bk (col bias), split hi/lo out
        gemm_bf16_nt<3, 2, 2><<<g, blk, 0, stream>>>(
            xH, xL, xH, (long)SD,  WkH, WkH, WkL, 0,  KH, KL, (long)SD, bk);
        // V = X*Wv^T + bv (col bias), bf16 out
        gemm_bf16_nt<1, 1, 2><<<g, blk, 0, stream>>>(
            xH, nullptr, nullptr, (long)SD,  WvH, nullptr, nullptr, 0,  Vb, nullptr, (long)SD, bv);
        // E = Qt * K^T-contraction (NT with PLAIN K), split 3-pass, fp32 out
        gemm_bf16_nt<3, 0, 0><<<g, blk, 0, stream>>>(
            QH, QL, QH, (long)SD,  KH, KH, KL, (long)SD,  Ew, nullptr, (long)SD, nullptr);
        // A = row-softmax(E), bf16
        softmax_bf16<<<dim3(cb * NDIM), dim3(256), 0, stream>>>(Ew, Ab);
        // Out = NT(V, A), fp32 -> d_out
        gemm_bf16_nt<1, 0, 0><<<g, blk, 0, stream>>>(
            Vb, nullptr, nullptr, (long)SD,  Ab, nullptr, nullptr, (long)SD,
            out + (size_t)b0 * SD, nullptr, (long)SD, nullptr);
    }
}

// Round 4
// 663.597 us; speedup vs baseline: 3.5376x; 1.2268x over previous
//
#include <hip/hip_runtime.h>
#include <hip/hip_bf16.h>

// SimpleSelfAttention, B=128, S=D=512, fp32 in/out, bf16 MFMA compute.
//   Qt[e,s] = sum_d Wq[e,d] X[s,d] + bq[e]     (split hi/lo 3-pass, split out)
//   K [s,e] = sum_d X[s,d] Wk[e,d] + bk[e]     (split hi/lo 3-pass, split out)
//   V [s,e] = sum_d X[s,d] Wv[e,d] + bv[e]     (1-pass bf16)
//   E[i,j]  = sum_k Qt[i,k] K[j,k]             (split 3-pass, fp32 out)
//   A = row-softmax(E)  (fp32 math, bf16 out)
//   Out[s,i] = sum_j V[s,j] A[i,j]             (1-pass, fp32 out)
// All matmuls are NT GEMM C[m,n] = sum_k A[m,k] B[n,k].
// Two GEMM engines:
//  - gemm8_nt: 256x256 tile, BK=64, 512 thr / 8 waves, 8-phase schedule
//    (T2 LDS swizzle + T3/T4 counted vmcnt + T5 setprio). Needs grid>=256
//    blocks -> chunk c>=64. LDS 128 KiB -> 1 block/CU.
//  - gemm_bf16_nt: R3's verified 128x128 2-phase kernel (fallback, small ws).

#define NDIM 512
#define NBATCH 128
constexpr size_t SD = (size_t)NDIM * NDIM;

typedef __attribute__((ext_vector_type(8))) short bf16x8;   // 8 bf16 = 4 VGPR
typedef __attribute__((ext_vector_type(4))) float f32x4;

typedef const __attribute__((address_space(1))) unsigned int* gas_ptr;
typedef __attribute__((address_space(3))) unsigned int* las_ptr;

struct alignas(8) us4 { unsigned short x, y, z, w; };
struct alignas(4) us2 { unsigned short x, y; };

__device__ __forceinline__ void gl_lds16(const void* g, void* lds) {
    // async global->LDS, 16B/lane; HW dest = wave-uniform base + lane*16
    __builtin_amdgcn_global_load_lds((gas_ptr)g, (las_ptr)lds, 16, 0, 0);
}
__device__ __forceinline__ unsigned short f2bf(float x) {
    return __builtin_bit_cast(unsigned short, __float2bfloat16(x));
}
__device__ __forceinline__ float bf2f(unsigned short u) {
    return __bfloat162float(__builtin_bit_cast(__hip_bfloat16, u));
}

// ===========================================================================
// 8-phase 256^2 NT GEMM (T2+T3+T4+T5).  C[m,n] = sum_seg sum_k A[m,k]B[n,k].
// 8 waves (wr=w>>2, wc=w&3); each wave owns a 64x32 piece of each of the four
// 128x128 C-quadrants. Per K-tile (BK=64): 4 phases, one C-quadrant each:
//   q=0:(Qr0,Qc0)  q=1:(0,1)  q=2:(1,1)  q=3:(1,0)
// Phase body: 12 ds_read_b128 (swizzled) -> stage 1 half-tile of K-tile t+1
// (order A0,B0,B1,A1; linear LDS dest, inverse-swizzled global src) ->
// vmcnt(4) -> barrier -> lgkmcnt(0)+sched_barrier -> setprio(1), 16 MFMA,
// setprio(0) -> barrier.  vmcnt(4) == "all but last 2 staged half-tiles
// complete"; consumption lag invariant hreq(p) <= p+2 holds for this order.
// LDS swizzle: 16B-slot s4 (0..7) stored at s4 ^ (row&7) within each 128B row.
template<int NSEG, int EPI, int BIAS>
__global__ __launch_bounds__(512, 2) void gemm8_nt(
    const unsigned short* a0, const unsigned short* a1, const unsigned short* a2, long sA,
    const unsigned short* b0, const unsigned short* b1, const unsigned short* b2, long sB,
    void* c0v, void* c1v, long sC, const float* __restrict__ bias)
{
    constexpr int NTK = NSEG * 8;                 // K-tiles of 64
    __shared__ unsigned short AS[2][256 * 64];    // [slot][m][k] swizzled
    __shared__ unsigned short BS[2][256 * 64];    // [slot][n][k] swizzled

    const int z  = blockIdx.z;
    const int m0 = blockIdx.y * 256, n0 = blockIdx.x * 256;
    const int tid = threadIdx.x;                  // 0..511
    const int l = tid & 63, w = tid >> 6;
    const int wr = w >> 2, wc = w & 3;

    const size_t zA = (size_t)z * sA + (size_t)m0 * NDIM;
    const size_t zB = (size_t)z * sB + (size_t)n0 * NDIM;

    // staging addressing: thread tid covers 16B granule; linear dest slot
    // (tid&7) holds data of logical slot (tid&7)^(row&7) -> pre-swizzle src.
    const int srow = tid >> 3;                                   // 0..63
    const int scol = (((tid & 7) ^ ((tid >> 3) & 7)) << 3);      // elems
    const int ldst = tid * 8;                                    // elems

    auto segA = [&](int s) {
        const unsigned short* p = a0;
        if constexpr (NSEG > 1) { if (s == 1) p = a1; else if (s == 2) p = a2; }
        return p;
    };
    auto segB = [&](int s) {
        const unsigned short* p = b0;
        if constexpr (NSEG > 1) { if (s == 1) p = b1; else if (s == 2) p = b2; }
        return p;
    };
    auto stageA = [&](int kt, int H, int slot) {
        const int seg = kt >> 3, k0 = (kt & 7) << 6;
        const unsigned short* g = segA(seg) + zA;
        #pragma unroll
        for (int j = 0; j < 2; ++j)
            gl_lds16(g + (size_t)(H * 128 + j * 64 + srow) * NDIM + k0 + scol,
                     &AS[slot][H * 8192 + j * 4096 + ldst]);
    };
    auto stageB = [&](int kt, int H, int slot) {
        const int seg = kt >> 3, k0 = (kt & 7) << 6;
        const unsigned short* g = segB(seg) + zB;
        #pragma unroll
        for (int j = 0; j < 2; ++j)
            gl_lds16(g + (size_t)(H * 128 + j * 64 + srow) * NDIM + k0 + scol,
                     &BS[slot][H * 8192 + j * 4096 + ldst]);
    };

    f32x4 acc[4][4][2] = {};   // [quadrant][mi][ni]

    // prologue: K-tile 0, halves h0..h3 = A0,B0,B1,A1; wait h0,h1 done
    stageA(0, 0, 0); stageB(0, 0, 0); stageB(0, 1, 0); stageA(0, 1, 0);
    asm volatile("s_waitcnt vmcnt(4)" ::: "memory");
    asm volatile("s_barrier" ::: "memory");

    for (int kt = 0; kt < NTK; ++kt) {
        const int cur = kt & 1, nxt = cur ^ 1;
        const int ktn = (kt + 1 < NTK) ? kt + 1 : kt;   // clamp: restage last
        #pragma unroll
        for (int q = 0; q < 4; ++q) {
            const int Qr = q >> 1;
            const int Qc = (q >> 1) ^ (q & 1);
            // 1. ds_read fragment subtile (12 x b128, swizzled)
            bf16x8 af[4][2], bfv[2][2];
            #pragma unroll
            for (int mi = 0; mi < 4; ++mi) {
                const int row = Qr * 128 + wr * 64 + mi * 16 + (l & 15);
                #pragma unroll
                for (int kk = 0; kk < 2; ++kk) {
                    const int s16 = ((kk << 2) + (l >> 4)) ^ (l & 7);
                    af[mi][kk] = *(const bf16x8*)&AS[cur][row * 64 + s16 * 8];
                }
            }
            #pragma unroll
            for (int ni = 0; ni < 2; ++ni) {
                const int row = Qc * 128 + wc * 32 + ni * 16 + (l & 15);
                #pragma unroll
                for (int kk = 0; kk < 2; ++kk) {
                    const int s16 = ((kk << 2) + (l >> 4)) ^ (l & 7);
                    bfv[ni][kk] = *(const bf16x8*)&BS[cur][row * 64 + s16 * 8];
                }
            }
            // 2. stage one half-tile of kt+1 (h_q: A0,B0,B1,A1)
            if      (q == 0) stageA(ktn, 0, nxt);
            else if (q == 1) stageB(ktn, 0, nxt);
            else if (q == 2) stageB(ktn, 1, nxt);
            else             stageA(ktn, 1, nxt);
            // 3. counted vmcnt (never 0) + barrier makes it workgroup-wide
            asm volatile("s_waitcnt vmcnt(4)" ::: "memory");
            asm volatile("s_barrier" ::: "memory");
            // 4. own ds_reads done; fence MFMA from hoisting (rule #18)
            asm volatile("s_waitcnt lgkmcnt(0)" ::: "memory");
            __builtin_amdgcn_sched_barrier(0);
            // 5. MFMA cluster (T5)
            __builtin_amdgcn_s_setprio(1);
            #pragma unroll
            for (int mi = 0; mi < 4; ++mi)
                #pragma unroll
                for (int ni = 0; ni < 2; ++ni)
                    #pragma unroll
                    for (int kk = 0; kk < 2; ++kk)
                        acc[q][mi][ni] = __builtin_amdgcn_mfma_f32_16x16x32_bf16(
                            af[mi][kk], bfv[ni][kk], acc[q][mi][ni], 0, 0, 0);
            __builtin_amdgcn_s_setprio(0);
            asm volatile("s_barrier" ::: "memory");   // WAR guard for slot swap
        }
    }
    // drain leftover stages before LDS dealloc at endpgm
    asm volatile("s_waitcnt vmcnt(0)" ::: "memory");

    // epilogue: C/D layout col = lane&15, row = (lane>>4)*4 + reg
    const size_t zc = (size_t)z * sC;
    const int cr = (l >> 4) << 2;
    const int cc = l & 15;
    #pragma unroll
    for (int q = 0; q < 4; ++q) {
        const int Qr = q >> 1, Qc = (q >> 1) ^ (q & 1);
        #pragma unroll
        for (int mi = 0; mi < 4; ++mi) {
            #pragma unroll
            for (int r = 0; r < 4; ++r) {
                const int m = m0 + Qr * 128 + wr * 64 + mi * 16 + cr + r;
                const float bm = (BIAS == 1) ? bias[m] : 0.0f;
                #pragma unroll
                for (int ni = 0; ni < 2; ++ni) {
                    const int n = n0 + Qc * 128 + wc * 32 + ni * 16 + cc;
                    float v = acc[q][mi][ni][r] + bm + ((BIAS == 2) ? bias[n] : 0.0f);
                    const size_t idx = zc + (size_t)m * NDIM + n;
                    if (EPI == 0) {
                        ((float*)c0v)[idx] = v;
                    } else if (EPI == 1) {
                        ((unsigned short*)c0v)[idx] = f2bf(v);
                    } else {
                        const unsigned short h = f2bf(v);
                        ((unsigned short*)c0v)[idx] = h;
                        ((unsigned short*)c1v)[idx] = f2bf(v - bf2f(h));
                    }
                }
            }
        }
    }
}

// ===========================================================================
// Fallback: R3's verified 128x128 2-phase NT GEMM (small-ws path).
template<int NSEG, int EPI, int BIAS>
__global__ __launch_bounds__(256) void gemm_bf16_nt(
    const unsigned short* a0, const unsigned short* a1, const unsigned short* a2, long sA,
    const unsigned short* b0, const unsigned short* b1, const unsigned short* b2, long sB,
    void* c0v, void* c1v, long sC, const float* __restrict__ bias)
{
    __shared__ unsigned short As[128 * 64];
    __shared__ unsigned short Bs[128 * 64];

    const int z  = blockIdx.z;
    const int m0 = blockIdx.y * 128, n0 = blockIdx.x * 128;
    const int tid = threadIdx.x;
    const int l = tid & 63, w = tid >> 6;
    const int wr = w >> 1, wc = w & 1;

    const int srow = tid >> 3;
    const int scol = (tid & 7) << 3;
    unsigned short* ldsA = &As[tid * 8];
    unsigned short* ldsB = &Bs[tid * 8];

    f32x4 acc[4][4] = {};

    const unsigned short* Asegs[3] = {a0, a1, a2};
    const unsigned short* Bsegs[3] = {b0, b1, b2};

    #pragma unroll
    for (int s = 0; s < NSEG; ++s) {
        const unsigned short* Ab = Asegs[s] + (size_t)z * sA + (size_t)m0 * NDIM;
        const unsigned short* Bb = Bsegs[s] + (size_t)z * sB + (size_t)n0 * NDIM;
        for (int k0 = 0; k0 < NDIM; k0 += 64) {
            __syncthreads();
            #pragma unroll
            for (int i = 0; i < 4; ++i) {
                gl_lds16(Ab + (size_t)(srow + i * 32) * NDIM + k0 + scol, ldsA + i * 2048);
                gl_lds16(Bb + (size_t)(srow + i * 32) * NDIM + k0 + scol, ldsB + i * 2048);
            }
            __syncthreads();
            #pragma unroll
            for (int kk = 0; kk < 2; ++kk) {
                bf16x8 af[4], bfv[4];
                #pragma unroll
                for (int f = 0; f < 4; ++f) {
                    af[f]  = *(const bf16x8*)&As[(wr * 64 + f * 16 + (l & 15)) * 64 + kk * 32 + (l >> 4) * 8];
                    bfv[f] = *(const bf16x8*)&Bs[(wc * 64 + f * 16 + (l & 15)) * 64 + kk * 32 + (l >> 4) * 8];
                }
                #pragma unroll
                for (int mi = 0; mi < 4; ++mi)
                    #pragma unroll
                    for (int ni = 0; ni < 4; ++ni)
                        acc[mi][ni] = __builtin_amdgcn_mfma_f32_16x16x32_bf16(
                            af[mi], bfv[ni], acc[mi][ni], 0, 0, 0);
            }
        }
    }

    const size_t zc = (size_t)z * sC;
    const int cr = (l >> 4) << 2;
    const int cc = l & 15;
    #pragma unroll
    for (int mi = 0; mi < 4; ++mi) {
        #pragma unroll
        for (int r = 0; r < 4; ++r) {
            const int m = m0 + wr * 64 + mi * 16 + cr + r;
            const float bm = (BIAS == 1) ? bias[m] : 0.0f;
            #pragma unroll
            for (int ni = 0; ni < 4; ++ni) {
                const int n = n0 + wc * 64 + ni * 16 + cc;
                float v = acc[mi][ni][r] + bm + ((BIAS == 2) ? bias[n] : 0.0f);
                const size_t idx = zc + (size_t)m * NDIM + n;
                if (EPI == 0) {
                    ((float*)c0v)[idx] = v;
                } else if (EPI == 1) {
                    ((unsigned short*)c0v)[idx] = f2bf(v);
                } else {
                    const unsigned short h = f2bf(v);
                    ((unsigned short*)c0v)[idx] = h;
                    ((unsigned short*)c1v)[idx] = f2bf(v - bf2f(h));
                }
            }
        }
    }
}

// ---------------------------------------------------------------------------
// row softmax: fp32 in, bf16 out; one 256-thread block per 512-elem row
__global__ __launch_bounds__(256) void softmax_bf16(
    const float* __restrict__ E, unsigned short* __restrict__ A)
{
    __shared__ float red[256];
    const float* p = E + (size_t)blockIdx.x * NDIM;
    unsigned short* q = A + (size_t)blockIdx.x * NDIM;
    const int t = threadIdx.x;

    const float2 v = *(const float2*)(p + 2 * t);
    red[t] = fmaxf(v.x, v.y);
    __syncthreads();
    for (int s = 128; s > 0; s >>= 1) {
        if (t < s) red[t] = fmaxf(red[t], red[t + s]);
        __syncthreads();
    }
    const float mx = red[0];
    __syncthreads();

    const float ex = __expf(v.x - mx), ey = __expf(v.y - mx);
    red[t] = ex + ey;
    __syncthreads();
    for (int s = 128; s > 0; s >>= 1) {
        if (t < s) red[t] += red[t + s];
        __syncthreads();
    }
    const float inv = 1.0f / red[0];
    us2 o; o.x = f2bf(ex * inv); o.y = f2bf(ey * inv);
    *(us2*)(q + 2 * t) = o;
}

// ---------------------------------------------------------------------------
// fp32 -> bf16 hi (+ optional lo = bf16(v - hi)), float4-vectorized
template<bool LO>
__global__ __launch_bounds__(256) void split_to_bf16(
    const float* __restrict__ src,
    unsigned short* __restrict__ hi, unsigned short* __restrict__ lo, int n4)
{
    const int i = blockIdx.x * 256 + threadIdx.x;
    if (i >= n4) return;
    const float4 v = ((const float4*)src)[i];
    us4 h;
    h.x = f2bf(v.x); h.y = f2bf(v.y); h.z = f2bf(v.z); h.w = f2bf(v.w);
    ((us4*)hi)[i] = h;
    if (LO) {
        us4 g;
        g.x = f2bf(v.x - bf2f(h.x)); g.y = f2bf(v.y - bf2f(h.y));
        g.z = f2bf(v.z - bf2f(h.z)); g.w = f2bf(v.w - bf2f(h.w));
        ((us4*)lo)[i] = g;
    }
}

// ---------------------------------------------------------------------------
extern "C" void kernel_launch(void* const* d_in, const int* in_sizes, int n_in,
                              void* d_out, int out_size, void* d_ws, size_t ws_size,
                              hipStream_t stream)
{
    const float* x  = (const float*)d_in[0];
    const float* Wq = (const float*)d_in[1];
    const float* bq = (const float*)d_in[2];
    const float* Wk = (const float*)d_in[3];
    const float* bk = (const float*)d_in[4];
    const float* Wv = (const float*)d_in[5];
    const float* bv = (const float*)d_in[6];
    float* out = (float*)d_out;

    // ws budget in u16-units of SD: 6 weight units + 10*c per-chunk units
    long units = (long)(ws_size / (2 * SD));
    long cl = (units - 6) / 10;
    if (cl < 1) cl = 1;
    int c = 1;
    while (c * 2 <= cl && c < 128) c *= 2;     // largest pow2 <= cl, <= 128
    const bool use8 = (c >= 64);               // 8-phase needs grid >= 256 blk
    if (!use8 && c > 32) c = 32;

    unsigned short* p = (unsigned short*)d_ws;
    auto take = [&](size_t elems) { unsigned short* r = p; p += elems; return r; };
    unsigned short* WqH = take(SD);
    unsigned short* WqL = take(SD);
    unsigned short* WkH = take(SD);
    unsigned short* WkL = take(SD);
    unsigned short* WvH = take(SD);
    unsigned short* xH  = take((size_t)c * SD);
    unsigned short* xL  = take((size_t)c * SD);
    unsigned short* QH  = take((size_t)c * SD);
    unsigned short* QL  = take((size_t)c * SD);
    unsigned short* KH  = take((size_t)c * SD);
    unsigned short* KL  = take((size_t)c * SD);
    unsigned short* Vb  = take((size_t)c * SD);
    unsigned short* Ab  = take((size_t)c * SD);
    float* Ew = (float*)p;   // c*SD fp32

    const int n4w = (int)(SD / 4);
    split_to_bf16<true ><<<dim3((n4w + 255) / 256), dim3(256), 0, stream>>>(Wq, WqH, WqL, n4w);
    split_to_bf16<true ><<<dim3((n4w + 255) / 256), dim3(256), 0, stream>>>(Wk, WkH, WkL, n4w);
    split_to_bf16<false><<<dim3((n4w + 255) / 256), dim3(256), 0, stream>>>(Wv, WvH, nullptr, n4w);

    for (int b0 = 0; b0 < NBATCH; b0 += c) {
        const int cb = (NBATCH - b0 < c) ? (NBATCH - b0) : c;
        const int n4 = (int)((size_t)cb * SD / 4);
        split_to_bf16<true><<<dim3((n4 + 255) / 256), dim3(256), 0, stream>>>(
            x + (size_t)b0 * SD, xH, xL, n4);

        if (use8) {
            const dim3 g(2, 2, cb), blk(512);
            gemm8_nt<3, 2, 1><<<g, blk, 0, stream>>>(
                WqH, WqL, WqH, 0,  xH, xH, xL, (long)SD,  QH, QL, (long)SD, bq);
            gemm8_nt<3, 2, 2><<<g, blk, 0, stream>>>(
                xH, xL, xH, (long)SD,  WkH, WkH, WkL, 0,  KH, KL, (long)SD, bk);
            gemm8_nt<1, 1, 2><<<g, blk, 0, stream>>>(
                xH, nullptr, nullptr, (long)SD,  WvH, nullptr, nullptr, 0,  Vb, nullptr, (long)SD, bv);
            gemm8_nt<3, 0, 0><<<g, blk, 0, stream>>>(
                QH, QL, QH, (long)SD,  KH, KH, KL, (long)SD,  Ew, nullptr, (long)SD, nullptr);
            softmax_bf16<<<dim3(cb * NDIM), dim3(256), 0, stream>>>(Ew, Ab);
            gemm8_nt<1, 0, 0><<<g, blk, 0, stream>>>(
                Vb, nullptr, nullptr, (long)SD,  Ab, nullptr, nullptr, (long)SD,
                out + (size_t)b0 * SD, nullptr, (long)SD, nullptr);
        } else {
            const dim3 g(4, 4, cb), blk(256);
            gemm_bf16_nt<3, 2, 1><<<g, blk, 0, stream>>>(
                WqH, WqL, WqH, 0,  xH, xH, xL, (long)SD,  QH, QL, (long)SD, bq);
            gemm_bf16_nt<3, 2, 2><<<g, blk, 0, stream>>>(
                xH, xL, xH, (long)SD,  WkH, WkH, WkL, 0,  KH, KL, (long)SD, bk);
            gemm_bf16_nt<1, 1, 2><<<g, blk, 0, stream>>>(
                xH, nullptr, nullptr, (long)SD,  WvH, nullptr, nullptr, 0,  Vb, nullptr, (long)SD, bv);
            gemm_bf16_nt<3, 0, 0><<<g, blk, 0, stream>>>(
                QH, QL, QH, (long)SD,  KH, KH, KL, (long)SD,  Ew, nullptr, (long)SD, nullptr);
            softmax_bf16<<<dim3(cb * NDIM), dim3(256), 0, stream>>>(Ew, Ab);
            gemm_bf16_nt<1, 0, 0><<<g, blk, 0, stream>>>(
                Vb, nullptr, nullptr, (long)SD,  Ab, nullptr, nullptr, (long)SD,
                out + (size_t)b0 * SD, nullptr, (long)SD, nullptr);
        }
    }
}

// Round 5
// 623.881 us; speedup vs baseline: 3.7628x; 1.0637x over previous
//
#include <hip/hip_runtime.h>
#include <hip/hip_bf16.h>

// SimpleSelfAttention, B=128, S=D=512, fp32 in/out, bf16 MFMA compute.
//   Qt[e,s] = sum_d Wq[e,d] X[s,d] + bq[e]     (split hi/lo 3-pass, split out)
//   K [s,e] = sum_d X[s,d] Wk[e,d] + bk[e]     (split hi/lo 3-pass, split out)
//   V [s,e] = sum_d X[s,d] Wv[e,d] + bv[e]     (1-pass bf16)
//   E[i,j]  = sum_k Qt[i,k] K[j,k]             (split 3-pass, fp32 out)
//   A = row-softmax(E)  (fp32 math, bf16 out)
//   Out[s,i] = sum_j V[s,j] A[i,j]             (1-pass, fp32 out)
// All matmuls are NT GEMM C[m,n] = sum_k A[m,k] B[n,k].
// gemm8_nt: 256x256 tile, BK=64, 512 thr / 8 waves, 4-phase/K-tile schedule
// (T2 swizzle + T3/T4 counted vmcnt + T5 setprio) with REGISTER FRAGMENT
// REUSE across phases: 24 ds_read_b128 per K-tile per wave (was 48 in R4 —
// LDS read was the critical path: 96KiB/phase/CU ~ 1150cyc vs 515cyc MFMA).

#define NDIM 512
#define NBATCH 128
constexpr size_t SD = (size_t)NDIM * NDIM;

typedef __attribute__((ext_vector_type(8))) short bf16x8;   // 8 bf16 = 4 VGPR
typedef __attribute__((ext_vector_type(4))) float f32x4;

typedef const __attribute__((address_space(1))) unsigned int* gas_ptr;
typedef __attribute__((address_space(3))) unsigned int* las_ptr;

struct alignas(8) us4 { unsigned short x, y, z, w; };
struct alignas(4) us2 { unsigned short x, y; };

__device__ __forceinline__ void gl_lds16(const void* g, void* lds) {
    // async global->LDS, 16B/lane; HW dest = wave-uniform base + lane*16
    __builtin_amdgcn_global_load_lds((gas_ptr)g, (las_ptr)lds, 16, 0, 0);
}
__device__ __forceinline__ unsigned short f2bf(float x) {
    return __builtin_bit_cast(unsigned short, __float2bfloat16(x));
}
__device__ __forceinline__ float bf2f(unsigned short u) {
    return __bfloat162float(__builtin_bit_cast(__hip_bfloat16, u));
}

// ===========================================================================
// 8-wave 256^2 NT GEMM. Per K-tile (BK=64): 4 phases, one 128x128 C-quadrant
// each, order (Qr,Qc) = (0,0),(0,1),(1,1),(1,0). Fragment reuse:
//   p0: read A0(8)+B0(4); stage A0(t+1); mfma acc[0][0] = A0*B0
//   p1: read B1(4);       stage B0(t+1); mfma acc[0][1] = A0*B1
//   p2: read A1(8,ovw);   stage B1(t+1); mfma acc[1][1] = A1*B1
//   p3: (no reads);       stage A1(t+1); mfma acc[1][0] = A1*B0
// Each phase: reads -> stage -> vmcnt(4) -> barrier -> lgkmcnt(0)+sched_bar
// -> setprio(1) 16 MFMA setprio(0) -> barrier.  vmcnt(4) never drains to 0;
// guard chain: p0 needs A0,B0 (oldest 4 of <=8 outstanding), p1 needs B1
// (oldest 2 of <=6), p2 needs A1 (oldest 2 of <=6) — all hold.
// LDS swizzle (T2): 16B-slot s4 stored at s4 ^ (row&7) within each 128B row;
// staging pre-swizzles the GLOBAL source, LDS dest stays linear (rule #21).
template<int NSEG, int EPI, int BIAS>
__global__ __launch_bounds__(512, 2) void gemm8_nt(
    const unsigned short* a0, const unsigned short* a1, const unsigned short* a2, long sA,
    const unsigned short* b0, const unsigned short* b1, const unsigned short* b2, long sB,
    void* c0v, void* c1v, long sC, const float* __restrict__ bias)
{
    constexpr int NTK = NSEG * 8;                 // K-tiles of 64
    __shared__ unsigned short AS[2][256 * 64];    // [slot][m][k] swizzled
    __shared__ unsigned short BS[2][256 * 64];    // [slot][n][k] swizzled

    const int z  = blockIdx.z;
    const int m0 = blockIdx.y * 256, n0 = blockIdx.x * 256;
    const int tid = threadIdx.x;                  // 0..511
    const int l = tid & 63, w = tid >> 6;
    const int wr = w >> 2, wc = w & 3;

    const size_t zA = (size_t)z * sA + (size_t)m0 * NDIM;
    const size_t zB = (size_t)z * sB + (size_t)n0 * NDIM;

    // staging: thread tid covers one 16B granule; linear LDS dest slot
    // (tid&7) holds logical slot (tid&7)^(row&7) -> pre-swizzled global src.
    const int srow = tid >> 3;                                   // 0..63
    const int scol = (((tid & 7) ^ ((tid >> 3) & 7)) << 3);      // elems
    const int ldst = tid * 8;                                    // elems

    auto segA = [&](int s) {
        const unsigned short* p = a0;
        if constexpr (NSEG > 1) { if (s == 1) p = a1; else if (s == 2) p = a2; }
        return p;
    };
    auto segB = [&](int s) {
        const unsigned short* p = b0;
        if constexpr (NSEG > 1) { if (s == 1) p = b1; else if (s == 2) p = b2; }
        return p;
    };
    auto stageA = [&](int kt, int H, int slot) {
        const int seg = kt >> 3, k0 = (kt & 7) << 6;
        const unsigned short* g = segA(seg) + zA;
        #pragma unroll
        for (int j = 0; j < 2; ++j)
            gl_lds16(g + (size_t)(H * 128 + j * 64 + srow) * NDIM + k0 + scol,
                     &AS[slot][H * 8192 + j * 4096 + ldst]);
    };
    auto stageB = [&](int kt, int H, int slot) {
        const int seg = kt >> 3, k0 = (kt & 7) << 6;
        const unsigned short* g = segB(seg) + zB;
        #pragma unroll
        for (int j = 0; j < 2; ++j)
            gl_lds16(g + (size_t)(H * 128 + j * 64 + srow) * NDIM + k0 + scol,
                     &BS[slot][H * 8192 + j * 4096 + ldst]);
    };

    // fragment readers (swizzled ds_read_b128)
    auto readA = [&](int slot, int H, bf16x8 (&dst)[4][2]) {
        #pragma unroll
        for (int mi = 0; mi < 4; ++mi) {
            const int row = H * 128 + wr * 64 + mi * 16 + (l & 15);
            #pragma unroll
            for (int kk = 0; kk < 2; ++kk) {
                const int s16 = ((kk << 2) + (l >> 4)) ^ (l & 7);
                dst[mi][kk] = *(const bf16x8*)&AS[slot][row * 64 + s16 * 8];
            }
        }
    };
    auto readB = [&](int slot, int H, bf16x8 (&dst)[2][2]) {
        #pragma unroll
        for (int ni = 0; ni < 2; ++ni) {
            const int row = H * 128 + wc * 32 + ni * 16 + (l & 15);
            #pragma unroll
            for (int kk = 0; kk < 2; ++kk) {
                const int s16 = ((kk << 2) + (l >> 4)) ^ (l & 7);
                dst[ni][kk] = *(const bf16x8*)&BS[slot][row * 64 + s16 * 8];
            }
        }
    };
    auto mfma16 = [&](f32x4 (&ac)[4][2], const bf16x8 (&a)[4][2],
                      const bf16x8 (&b)[2][2]) {
        __builtin_amdgcn_s_setprio(1);
        #pragma unroll
        for (int mi = 0; mi < 4; ++mi)
            #pragma unroll
            for (int ni = 0; ni < 2; ++ni)
                #pragma unroll
                for (int kk = 0; kk < 2; ++kk)
                    ac[mi][ni] = __builtin_amdgcn_mfma_f32_16x16x32_bf16(
                        a[mi][kk], b[ni][kk], ac[mi][ni], 0, 0, 0);
        __builtin_amdgcn_s_setprio(0);
    };

    f32x4 acc[2][2][4][2] = {};   // [Qr][Qc][mi][ni]

    // prologue: K-tile 0, halves A0,B0,B1,A1 into slot 0; wait A0,B0
    stageA(0, 0, 0); stageB(0, 0, 0); stageB(0, 1, 0); stageA(0, 1, 0);
    asm volatile("s_waitcnt vmcnt(4)" ::: "memory");
    asm volatile("s_barrier" ::: "memory");

    for (int kt = 0; kt < NTK; ++kt) {
        const int cur = kt & 1, nxt = cur ^ 1;
        const int ktn = (kt + 1 < NTK) ? kt + 1 : kt;   // clamp: restage last
        bf16x8 af[4][2], b0f[2][2], b1f[2][2];

        // ---- phase 0: quad (0,0) = A0*B0
        readA(cur, 0, af); readB(cur, 0, b0f);
        stageA(ktn, 0, nxt);
        asm volatile("s_waitcnt vmcnt(4)" ::: "memory");
        asm volatile("s_barrier" ::: "memory");
        asm volatile("s_waitcnt lgkmcnt(0)" ::: "memory");
        __builtin_amdgcn_sched_barrier(0);
        mfma16(acc[0][0], af, b0f);
        asm volatile("s_barrier" ::: "memory");

        // ---- phase 1: quad (0,1) = A0*B1 (reuse af)
        readB(cur, 1, b1f);
        stageB(ktn, 0, nxt);
        asm volatile("s_waitcnt vmcnt(4)" ::: "memory");
        asm volatile("s_barrier" ::: "memory");
        asm volatile("s_waitcnt lgkmcnt(0)" ::: "memory");
        __builtin_amdgcn_sched_barrier(0);
        mfma16(acc[0][1], af, b1f);
        asm volatile("s_barrier" ::: "memory");

        // ---- phase 2: quad (1,1) = A1*B1 (overwrite af, reuse b1f)
        readA(cur, 1, af);
        stageB(ktn, 1, nxt);
        asm volatile("s_waitcnt vmcnt(4)" ::: "memory");
        asm volatile("s_barrier" ::: "memory");
        asm volatile("s_waitcnt lgkmcnt(0)" ::: "memory");
        __builtin_amdgcn_sched_barrier(0);
        mfma16(acc[1][1], af, b1f);
        asm volatile("s_barrier" ::: "memory");

        // ---- phase 3: quad (1,0) = A1*B0 (reuse af, b0f; no new reads)
        stageA(ktn, 1, nxt);
        asm volatile("s_waitcnt vmcnt(4)" ::: "memory");
        asm volatile("s_barrier" ::: "memory");
        __builtin_amdgcn_sched_barrier(0);
        mfma16(acc[1][0], af, b0f);
        asm volatile("s_barrier" ::: "memory");
    }
    // drain leftover stages before LDS dealloc at endpgm
    asm volatile("s_waitcnt vmcnt(0)" ::: "memory");

    // epilogue: C/D layout col = lane&15, row = (lane>>4)*4 + reg
    const size_t zc = (size_t)z * sC;
    const int cr = (l >> 4) << 2;
    const int cc = l & 15;
    #pragma unroll
    for (int Qr = 0; Qr < 2; ++Qr) {
        #pragma unroll
        for (int Qc = 0; Qc < 2; ++Qc) {
            #pragma unroll
            for (int mi = 0; mi < 4; ++mi) {
                #pragma unroll
                for (int r = 0; r < 4; ++r) {
                    const int m = m0 + Qr * 128 + wr * 64 + mi * 16 + cr + r;
                    const float bm = (BIAS == 1) ? bias[m] : 0.0f;
                    #pragma unroll
                    for (int ni = 0; ni < 2; ++ni) {
                        const int n = n0 + Qc * 128 + wc * 32 + ni * 16 + cc;
                        float v = acc[Qr][Qc][mi][ni][r] + bm + ((BIAS == 2) ? bias[n] : 0.0f);
                        const size_t idx = zc + (size_t)m * NDIM + n;
                        if (EPI == 0) {
                            ((float*)c0v)[idx] = v;
                        } else if (EPI == 1) {
                            ((unsigned short*)c0v)[idx] = f2bf(v);
                        } else {
                            const unsigned short h = f2bf(v);
                            ((unsigned short*)c0v)[idx] = h;
                            ((unsigned short*)c1v)[idx] = f2bf(v - bf2f(h));
                        }
                    }
                }
            }
        }
    }
}

// ===========================================================================
// Fallback: R3's verified 128x128 2-phase NT GEMM (small-ws path).
template<int NSEG, int EPI, int BIAS>
__global__ __launch_bounds__(256) void gemm_bf16_nt(
    const unsigned short* a0, const unsigned short* a1, const unsigned short* a2, long sA,
    const unsigned short* b0, const unsigned short* b1, const unsigned short* b2, long sB,
    void* c0v, void* c1v, long sC, const float* __restrict__ bias)
{
    __shared__ unsigned short As[128 * 64];
    __shared__ unsigned short Bs[128 * 64];

    const int z  = blockIdx.z;
    const int m0 = blockIdx.y * 128, n0 = blockIdx.x * 128;
    const int tid = threadIdx.x;
    const int l = tid & 63, w = tid >> 6;
    const int wr = w >> 1, wc = w & 1;

    const int srow = tid >> 3;
    const int scol = (tid & 7) << 3;
    unsigned short* ldsA = &As[tid * 8];
    unsigned short* ldsB = &Bs[tid * 8];

    f32x4 acc[4][4] = {};

    const unsigned short* Asegs[3] = {a0, a1, a2};
    const unsigned short* Bsegs[3] = {b0, b1, b2};

    #pragma unroll
    for (int s = 0; s < NSEG; ++s) {
        const unsigned short* Ab = Asegs[s] + (size_t)z * sA + (size_t)m0 * NDIM;
        const unsigned short* Bb = Bsegs[s] + (size_t)z * sB + (size_t)n0 * NDIM;
        for (int k0 = 0; k0 < NDIM; k0 += 64) {
            __syncthreads();
            #pragma unroll
            for (int i = 0; i < 4; ++i) {
                gl_lds16(Ab + (size_t)(srow + i * 32) * NDIM + k0 + scol, ldsA + i * 2048);
                gl_lds16(Bb + (size_t)(srow + i * 32) * NDIM + k0 + scol, ldsB + i * 2048);
            }
            __syncthreads();
            #pragma unroll
            for (int kk = 0; kk < 2; ++kk) {
                bf16x8 af[4], bfv[4];
                #pragma unroll
                for (int f = 0; f < 4; ++f) {
                    af[f]  = *(const bf16x8*)&As[(wr * 64 + f * 16 + (l & 15)) * 64 + kk * 32 + (l >> 4) * 8];
                    bfv[f] = *(const bf16x8*)&Bs[(wc * 64 + f * 16 + (l & 15)) * 64 + kk * 32 + (l >> 4) * 8];
                }
                #pragma unroll
                for (int mi = 0; mi < 4; ++mi)
                    #pragma unroll
                    for (int ni = 0; ni < 4; ++ni)
                        acc[mi][ni] = __builtin_amdgcn_mfma_f32_16x16x32_bf16(
                            af[mi], bfv[ni], acc[mi][ni], 0, 0, 0);
            }
        }
    }

    const size_t zc = (size_t)z * sC;
    const int cr = (l >> 4) << 2;
    const int cc = l & 15;
    #pragma unroll
    for (int mi = 0; mi < 4; ++mi) {
        #pragma unroll
        for (int r = 0; r < 4; ++r) {
            const int m = m0 + wr * 64 + mi * 16 + cr + r;
            const float bm = (BIAS == 1) ? bias[m] : 0.0f;
            #pragma unroll
            for (int ni = 0; ni < 4; ++ni) {
                const int n = n0 + wc * 64 + ni * 16 + cc;
                float v = acc[mi][ni][r] + bm + ((BIAS == 2) ? bias[n] : 0.0f);
                const size_t idx = zc + (size_t)m * NDIM + n;
                if (EPI == 0) {
                    ((float*)c0v)[idx] = v;
                } else if (EPI == 1) {
                    ((unsigned short*)c0v)[idx] = f2bf(v);
                } else {
                    const unsigned short h = f2bf(v);
                    ((unsigned short*)c0v)[idx] = h;
                    ((unsigned short*)c1v)[idx] = f2bf(v - bf2f(h));
                }
            }
        }
    }
}

// ---------------------------------------------------------------------------
// row softmax: fp32 in, bf16 out; one 256-thread block per 512-elem row
__global__ __launch_bounds__(256) void softmax_bf16(
    const float* __restrict__ E, unsigned short* __restrict__ A)
{
    __shared__ float red[256];
    const float* p = E + (size_t)blockIdx.x * NDIM;
    unsigned short* q = A + (size_t)blockIdx.x * NDIM;
    const int t = threadIdx.x;

    const float2 v = *(const float2*)(p + 2 * t);
    red[t] = fmaxf(v.x, v.y);
    __syncthreads();
    for (int s = 128; s > 0; s >>= 1) {
        if (t < s) red[t] = fmaxf(red[t], red[t + s]);
        __syncthreads();
    }
    const float mx = red[0];
    __syncthreads();

    const float ex = __expf(v.x - mx), ey = __expf(v.y - mx);
    red[t] = ex + ey;
    __syncthreads();
    for (int s = 128; s > 0; s >>= 1) {
        if (t < s) red[t] += red[t + s];
        __syncthreads();
    }
    const float inv = 1.0f / red[0];
    us2 o; o.x = f2bf(ex * inv); o.y = f2bf(ey * inv);
    *(us2*)(q + 2 * t) = o;
}

// ---------------------------------------------------------------------------
// fp32 -> bf16 hi (+ optional lo = bf16(v - hi)), float4-vectorized
template<bool LO>
__global__ __launch_bounds__(256) void split_to_bf16(
    const float* __restrict__ src,
    unsigned short* __restrict__ hi, unsigned short* __restrict__ lo, int n4)
{
    const int i = blockIdx.x * 256 + threadIdx.x;
    if (i >= n4) return;
    const float4 v = ((const float4*)src)[i];
    us4 h;
    h.x = f2bf(v.x); h.y = f2bf(v.y); h.z = f2bf(v.z); h.w = f2bf(v.w);
    ((us4*)hi)[i] = h;
    if (LO) {
        us4 g;
        g.x = f2bf(v.x - bf2f(h.x)); g.y = f2bf(v.y - bf2f(h.y));
        g.z = f2bf(v.z - bf2f(h.z)); g.w = f2bf(v.w - bf2f(h.w));
        ((us4*)lo)[i] = g;
    }
}

// ---------------------------------------------------------------------------
extern "C" void kernel_launch(void* const* d_in, const int* in_sizes, int n_in,
                              void* d_out, int out_size, void* d_ws, size_t ws_size,
                              hipStream_t stream)
{
    const float* x  = (const float*)d_in[0];
    const float* Wq = (const float*)d_in[1];
    const float* bq = (const float*)d_in[2];
    const float* Wk = (const float*)d_in[3];
    const float* bk = (const float*)d_in[4];
    const float* Wv = (const float*)d_in[5];
    const float* bv = (const float*)d_in[6];
    float* out = (float*)d_out;

    // ws budget in u16-units of SD: 6 weight units + 10*c per-chunk units
    long units = (long)(ws_size / (2 * SD));
    long cl = (units - 6) / 10;
    if (cl < 1) cl = 1;
    int c = 1;
    while (c * 2 <= cl && c < 128) c *= 2;     // largest pow2 <= cl, <= 128
    const bool use8 = (c >= 64);               // 8-phase needs grid >= 256 blk
    if (!use8 && c > 32) c = 32;

    unsigned short* p = (unsigned short*)d_ws;
    auto take = [&](size_t elems) { unsigned short* r = p; p += elems; return r; };
    unsigned short* WqH = take(SD);
    unsigned short* WqL = take(SD);
    unsigned short* WkH = take(SD);
    unsigned short* WkL = take(SD);
    unsigned short* WvH = take(SD);
    unsigned short* xH  = take((size_t)c * SD);
    unsigned short* xL  = take((size_t)c * SD);
    unsigned short* QH  = take((size_t)c * SD);
    unsigned short* QL  = take((size_t)c * SD);
    unsigned short* KH  = take((size_t)c * SD);
    unsigned short* KL  = take((size_t)c * SD);
    unsigned short* Vb  = take((size_t)c * SD);
    unsigned short* Ab  = take((size_t)c * SD);
    float* Ew = (float*)p;   // c*SD fp32

    const int n4w = (int)(SD / 4);
    split_to_bf16<true ><<<dim3((n4w + 255) / 256), dim3(256), 0, stream>>>(Wq, WqH, WqL, n4w);
    split_to_bf16<true ><<<dim3((n4w + 255) / 256), dim3(256), 0, stream>>>(Wk, WkH, WkL, n4w);
    split_to_bf16<false><<<dim3((n4w + 255) / 256), dim3(256), 0, stream>>>(Wv, WvH, nullptr, n4w);

    for (int b0 = 0; b0 < NBATCH; b0 += c) {
        const int cb = (NBATCH - b0 < c) ? (NBATCH - b0) : c;
        const int n4 = (int)((size_t)cb * SD / 4);
        split_to_bf16<true><<<dim3((n4 + 255) / 256), dim3(256), 0, stream>>>(
            x + (size_t)b0 * SD, xH, xL, n4);

        if (use8) {
            const dim3 g(2, 2, cb), blk(512);
            gemm8_nt<3, 2, 1><<<g, blk, 0, stream>>>(
                WqH, WqL, WqH, 0,  xH, xH, xL, (long)SD,  QH, QL, (long)SD, bq);
            gemm8_nt<3, 2, 2><<<g, blk, 0, stream>>>(
                xH, xL, xH, (long)SD,  WkH, WkH, WkL, 0,  KH, KL, (long)SD, bk);
            gemm8_nt<1, 1, 2><<<g, blk, 0, stream>>>(
                xH, nullptr, nullptr, (long)SD,  WvH, nullptr, nullptr, 0,  Vb, nullptr, (long)SD, bv);
            gemm8_nt<3, 0, 0><<<g, blk, 0, stream>>>(
                QH, QL, QH, (long)SD,  KH, KH, KL, (long)SD,  Ew, nullptr, (long)SD, nullptr);
            softmax_bf16<<<dim3(cb * NDIM), dim3(256), 0, stream>>>(Ew, Ab);
            gemm8_nt<1, 0, 0><<<g, blk, 0, stream>>>(
                Vb, nullptr, nullptr, (long)SD,  Ab, nullptr, nullptr, (long)SD,
                out + (size_t)b0 * SD, nullptr, (long)SD, nullptr);
        } else {
            const dim3 g(4, 4, cb), blk(256);
            gemm_bf16_nt<3, 2, 1><<<g, blk, 0, stream>>>(
                WqH, WqL, WqH, 0,  xH, xH, xL, (long)SD,  QH, QL, (long)SD, bq);
            gemm_bf16_nt<3, 2, 2><<<g, blk, 0, stream>>>(
                xH, xL, xH, (long)SD,  WkH, WkH, WkL, 0,  KH, KL, (long)SD, bk);
            gemm_bf16_nt<1, 1, 2><<<g, blk, 0, stream>>>(
                xH, nullptr, nullptr, (long)SD,  WvH, nullptr, nullptr, 0,  Vb, nullptr, (long)SD, bv);
            gemm_bf16_nt<3, 0, 0><<<g, blk, 0, stream>>>(
                QH, QL, QH, (long)SD,  KH, KH, KL, (long)SD,  Ew, nullptr, (long)SD, nullptr);
            softmax_bf16<<<dim3(cb * NDIM), dim3(256), 0, stream>>>(Ew, Ab);
            gemm_bf16_nt<1, 0, 0><<<g, blk, 0, stream>>>(
                Vb, nullptr, nullptr, (long)SD,  Ab, nullptr, nullptr, (long)SD,
                out + (size_t)b0 * SD, nullptr, (long)SD, nullptr);
        }
    }
}

// Round 7
// 607.678 us; speedup vs baseline: 3.8631x; 1.0267x over previous
//
#include <hip/hip_runtime.h>
#include <hip/hip_bf16.h>

// SimpleSelfAttention, B=128, S=D=512, fp32 in/out, bf16 MFMA compute.
//   Qt[e,s] = sum_d Wq[e,d] X[s,d] + bq[e]     (split hi/lo 3-pass, split out)
//   K [s,e] = sum_d X[s,d] Wk[e,d] + bk[e]     (split hi/lo 3-pass, split out)
//   V [s,e] = sum_d X[s,d] Wv[e,d] + bv[e]     (1-pass bf16)
//   E[i,j]  = sum_k Qt[i,k] K[j,k]             (split 3-pass, fp32 out)
//   A = row-softmax(E)  (fp32 math, bf16 out)
//   Out[s,i] = sum_j V[s,j] A[i,j]             (1-pass, fp32 out)
// All matmuls are NT GEMM C[m,n] = sum_k A[m,k] B[n,k].
// gemm8_nt: 256x256 tile, BK=64, 512 thr / 8 waves, 4-phase/K-tile,
// fragment reuse, T2 swizzle, T5 setprio, T1 XCD swizzle.
// R7: phase order {stage -> vmcnt(6) -> barrier -> ds_read -> lgkm -> mfma};
// reads sit AFTER the guard that covers them (R6 had them before -> race on
// B0: at t-1p3's vmcnt(6), t-1p1's B0 stage could still be outstanding).
// Single barrier per phase: a wave reaches tile t+1's stage of slot cur(t)
// only after the t-p3 barrier, and every wave drains its reads (lgkmcnt(0))
// inside each phase -> WAR across slot swap is barrier-ordered.

#define NDIM 512
#define NBATCH 128
constexpr size_t SD = (size_t)NDIM * NDIM;

typedef __attribute__((ext_vector_type(8))) short bf16x8;   // 8 bf16 = 4 VGPR
typedef __attribute__((ext_vector_type(4))) float f32x4;

typedef const __attribute__((address_space(1))) unsigned int* gas_ptr;
typedef __attribute__((address_space(3))) unsigned int* las_ptr;

struct alignas(8) us4 { unsigned short x, y, z, w; };
struct alignas(4) us2 { unsigned short x, y; };

__device__ __forceinline__ void gl_lds16(const void* g, void* lds) {
    // async global->LDS, 16B/lane; HW dest = wave-uniform base + lane*16
    __builtin_amdgcn_global_load_lds((gas_ptr)g, (las_ptr)lds, 16, 0, 0);
}
__device__ __forceinline__ unsigned short f2bf(float x) {
    return __builtin_bit_cast(unsigned short, __float2bfloat16(x));
}
__device__ __forceinline__ float bf2f(unsigned short u) {
    return __bfloat162float(__builtin_bit_cast(__hip_bfloat16, u));
}

// ===========================================================================
// 8-wave 256^2 NT GEMM, 1D grid (4 blocks/batch), XCD-swizzled.
// Per K-tile (BK=64), stage order A0,B0,B1,A1 (2 gl_lds each):
//   p0: stage A0(t+1); GUARD; read A0,B0(t); mfma acc[0][0]=A0*B0
//   p1: stage B0(t+1); GUARD; read B1(t);    mfma acc[0][1]=A0*B1
//   p2: stage B1(t+1); GUARD; read A1(t,ovw);mfma acc[1][1]=A1*B1
//   p3: stage A1(t+1); GUARD; (no reads)     mfma acc[1][0]=A1*B0
// GUARD = vmcnt(6)+barrier. At each guard, newest 6 outstanding = the last
// 3 phases' issues; every half-tile consumed after the guard was staged >=3
// phases earlier -> complete. vmcnt(8) would break p0's B0. Prologue's 8
// loads are covered by p0's own guard (oldest 4 = A0,B0 forced complete).
// LDS swizzle (T2): 16B-slot s4 stored at s4 ^ (row&7) within each 128B row;
// staging pre-swizzles the GLOBAL source, LDS dest stays linear (rule #21).
template<int NSEG, int EPI, int BIAS>
__global__ __launch_bounds__(512, 2) void gemm8_nt(
    const unsigned short* a0, const unsigned short* a1, const unsigned short* a2, long sA,
    const unsigned short* b0, const unsigned short* b1, const unsigned short* b2, long sB,
    void* c0v, void* c1v, long sC, const float* __restrict__ bias)
{
    constexpr int NTK = NSEG * 8;                 // K-tiles of 64
    __shared__ unsigned short AS[2][256 * 64];    // [slot][m][k] swizzled
    __shared__ unsigned short BS[2][256 * 64];    // [slot][n][k] swizzled

    // T1: bijective XCD swizzle (nwg % 8 == 0 for c>=64): consecutive wg
    // (the 4 quadrant-blocks of one batch) land on the SAME XCD.
    const int nwg = gridDim.x;
    int id = blockIdx.x;
    int wg = ((nwg & 7) == 0) ? ((id & 7) * (nwg >> 3) + (id >> 3)) : id;
    const int z  = wg >> 2;
    const int m0 = ((wg >> 1) & 1) * 256;
    const int n0 = (wg & 1) * 256;

    const int tid = threadIdx.x;                  // 0..511
    const int l = tid & 63, w = tid >> 6;
    const int wr = w >> 2, wc = w & 3;

    const size_t zA = (size_t)z * sA + (size_t)m0 * NDIM;
    const size_t zB = (size_t)z * sB + (size_t)n0 * NDIM;

    // staging: thread tid covers one 16B granule; linear LDS dest slot
    // (tid&7) holds logical slot (tid&7)^(row&7) -> pre-swizzled global src.
    const int srow = tid >> 3;                                   // 0..63
    const int scol = (((tid & 7) ^ ((tid >> 3) & 7)) << 3);      // elems
    const int ldst = tid * 8;                                    // elems

    auto segA = [&](int s) {
        const unsigned short* p = a0;
        if constexpr (NSEG > 1) { if (s == 1) p = a1; else if (s == 2) p = a2; }
        return p;
    };
    auto segB = [&](int s) {
        const unsigned short* p = b0;
        if constexpr (NSEG > 1) { if (s == 1) p = b1; else if (s == 2) p = b2; }
        return p;
    };
    auto stageA = [&](int kt, int H, int slot) {
        const int seg = kt >> 3, k0 = (kt & 7) << 6;
        const unsigned short* g = segA(seg) + zA;
        #pragma unroll
        for (int j = 0; j < 2; ++j)
            gl_lds16(g + (size_t)(H * 128 + j * 64 + srow) * NDIM + k0 + scol,
                     &AS[slot][H * 8192 + j * 4096 + ldst]);
    };
    auto stageB = [&](int kt, int H, int slot) {
        const int seg = kt >> 3, k0 = (kt & 7) << 6;
        const unsigned short* g = segB(seg) + zB;
        #pragma unroll
        for (int j = 0; j < 2; ++j)
            gl_lds16(g + (size_t)(H * 128 + j * 64 + srow) * NDIM + k0 + scol,
                     &BS[slot][H * 8192 + j * 4096 + ldst]);
    };

    // fragment readers (swizzled ds_read_b128)
    auto readA = [&](int slot, int H, bf16x8 (&dst)[4][2]) {
        #pragma unroll
        for (int mi = 0; mi < 4; ++mi) {
            const int row = H * 128 + wr * 64 + mi * 16 + (l & 15);
            #pragma unroll
            for (int kk = 0; kk < 2; ++kk) {
                const int s16 = ((kk << 2) + (l >> 4)) ^ (l & 7);
                dst[mi][kk] = *(const bf16x8*)&AS[slot][row * 64 + s16 * 8];
            }
        }
    };
    auto readB = [&](int slot, int H, bf16x8 (&dst)[2][2]) {
        #pragma unroll
        for (int ni = 0; ni < 2; ++ni) {
            const int row = H * 128 + wc * 32 + ni * 16 + (l & 15);
            #pragma unroll
            for (int kk = 0; kk < 2; ++kk) {
                const int s16 = ((kk << 2) + (l >> 4)) ^ (l & 7);
                dst[ni][kk] = *(const bf16x8*)&BS[slot][row * 64 + s16 * 8];
            }
        }
    };
    auto mfma16 = [&](f32x4 (&ac)[4][2], const bf16x8 (&a)[4][2],
                      const bf16x8 (&b)[2][2]) {
        __builtin_amdgcn_s_setprio(1);
        #pragma unroll
        for (int mi = 0; mi < 4; ++mi)
            #pragma unroll
            for (int ni = 0; ni < 2; ++ni)
                #pragma unroll
                for (int kk = 0; kk < 2; ++kk)
                    ac[mi][ni] = __builtin_amdgcn_mfma_f32_16x16x32_bf16(
                        a[mi][kk], b[ni][kk], ac[mi][ni], 0, 0, 0);
        __builtin_amdgcn_s_setprio(0);
    };

    f32x4 acc[2][2][4][2] = {};   // [Qr][Qc][mi][ni]

    // prologue: stage K-tile 0 halves A0,B0,B1,A1 into slot 0 (no wait;
    // phase 0's guard forces the oldest 4 loads (A0,B0) complete)
    stageA(0, 0, 0); stageB(0, 0, 0); stageB(0, 1, 0); stageA(0, 1, 0);

    for (int kt = 0; kt < NTK; ++kt) {
        const int cur = kt & 1, nxt = cur ^ 1;
        const int ktn = (kt + 1 < NTK) ? kt + 1 : kt;   // clamp: restage last
        bf16x8 af[4][2], b0f[2][2], b1f[2][2];

        // ---- phase 0: quad (0,0) = A0*B0
        stageA(ktn, 0, nxt);
        asm volatile("s_waitcnt vmcnt(6)" ::: "memory");
        asm volatile("s_barrier" ::: "memory");
        readA(cur, 0, af); readB(cur, 0, b0f);
        asm volatile("s_waitcnt lgkmcnt(0)" ::: "memory");
        __builtin_amdgcn_sched_barrier(0);
        mfma16(acc[0][0], af, b0f);

        // ---- phase 1: quad (0,1) = A0*B1 (reuse af)
        stageB(ktn, 0, nxt);
        asm volatile("s_waitcnt vmcnt(6)" ::: "memory");
        asm volatile("s_barrier" ::: "memory");
        readB(cur, 1, b1f);
        asm volatile("s_waitcnt lgkmcnt(0)" ::: "memory");
        __builtin_amdgcn_sched_barrier(0);
        mfma16(acc[0][1], af, b1f);

        // ---- phase 2: quad (1,1) = A1*B1 (overwrite af, reuse b1f)
        stageB(ktn, 1, nxt);
        asm volatile("s_waitcnt vmcnt(6)" ::: "memory");
        asm volatile("s_barrier" ::: "memory");
        readA(cur, 1, af);
        asm volatile("s_waitcnt lgkmcnt(0)" ::: "memory");
        __builtin_amdgcn_sched_barrier(0);
        mfma16(acc[1][1], af, b1f);

        // ---- phase 3: quad (1,0) = A1*B0 (reuse af, b0f; no new reads)
        stageA(ktn, 1, nxt);
        asm volatile("s_waitcnt vmcnt(6)" ::: "memory");
        asm volatile("s_barrier" ::: "memory");
        __builtin_amdgcn_sched_barrier(0);
        mfma16(acc[1][0], af, b0f);
    }
    // drain leftover stages before LDS dealloc at endpgm
    asm volatile("s_waitcnt vmcnt(0)" ::: "memory");

    // epilogue: C/D layout col = lane&15, row = (lane>>4)*4 + reg
    const size_t zc = (size_t)z * sC;
    const int cr = (l >> 4) << 2;
    const int cc = l & 15;
    #pragma unroll
    for (int Qr = 0; Qr < 2; ++Qr) {
        #pragma unroll
        for (int Qc = 0; Qc < 2; ++Qc) {
            #pragma unroll
            for (int mi = 0; mi < 4; ++mi) {
                #pragma unroll
                for (int r = 0; r < 4; ++r) {
                    const int m = m0 + Qr * 128 + wr * 64 + mi * 16 + cr + r;
                    const float bm = (BIAS == 1) ? bias[m] : 0.0f;
                    #pragma unroll
                    for (int ni = 0; ni < 2; ++ni) {
                        const int n = n0 + Qc * 128 + wc * 32 + ni * 16 + cc;
                        float v = acc[Qr][Qc][mi][ni][r] + bm + ((BIAS == 2) ? bias[n] : 0.0f);
                        const size_t idx = zc + (size_t)m * NDIM + n;
                        if (EPI == 0) {
                            ((float*)c0v)[idx] = v;
                        } else if (EPI == 1) {
                            ((unsigned short*)c0v)[idx] = f2bf(v);
                        } else {
                            const unsigned short h = f2bf(v);
                            ((unsigned short*)c0v)[idx] = h;
                            ((unsigned short*)c1v)[idx] = f2bf(v - bf2f(h));
                        }
                    }
                }
            }
        }
    }
}

// ===========================================================================
// Fallback: R3's verified 128x128 2-phase NT GEMM (small-ws path).
template<int NSEG, int EPI, int BIAS>
__global__ __launch_bounds__(256) void gemm_bf16_nt(
    const unsigned short* a0, const unsigned short* a1, const unsigned short* a2, long sA,
    const unsigned short* b0, const unsigned short* b1, const unsigned short* b2, long sB,
    void* c0v, void* c1v, long sC, const float* __restrict__ bias)
{
    __shared__ unsigned short As[128 * 64];
    __shared__ unsigned short Bs[128 * 64];

    const int z  = blockIdx.z;
    const int m0 = blockIdx.y * 128, n0 = blockIdx.x * 128;
    const int tid = threadIdx.x;
    const int l = tid & 63, w = tid >> 6;
    const int wr = w >> 1, wc = w & 1;

    const int srow = tid >> 3;
    const int scol = (tid & 7) << 3;
    unsigned short* ldsA = &As[tid * 8];
    unsigned short* ldsB = &Bs[tid * 8];

    f32x4 acc[4][4] = {};

    const unsigned short* Asegs[3] = {a0, a1, a2};
    const unsigned short* Bsegs[3] = {b0, b1, b2};

    #pragma unroll
    for (int s = 0; s < NSEG; ++s) {
        const unsigned short* Ab = Asegs[s] + (size_t)z * sA + (size_t)m0 * NDIM;
        const unsigned short* Bb = Bsegs[s] + (size_t)z * sB + (size_t)n0 * NDIM;
        for (int k0 = 0; k0 < NDIM; k0 += 64) {
            __syncthreads();
            #pragma unroll
            for (int i = 0; i < 4; ++i) {
                gl_lds16(Ab + (size_t)(srow + i * 32) * NDIM + k0 + scol, ldsA + i * 2048);
                gl_lds16(Bb + (size_t)(srow + i * 32) * NDIM + k0 + scol, ldsB + i * 2048);
            }
            __syncthreads();
            #pragma unroll
            for (int kk = 0; kk < 2; ++kk) {
                bf16x8 af[4], bfv[4];
                #pragma unroll
                for (int f = 0; f < 4; ++f) {
                    af[f]  = *(const bf16x8*)&As[(wr * 64 + f * 16 + (l & 15)) * 64 + kk * 32 + (l >> 4) * 8];
                    bfv[f] = *(const bf16x8*)&Bs[(wc * 64 + f * 16 + (l & 15)) * 64 + kk * 32 + (l >> 4) * 8];
                }
                #pragma unroll
                for (int mi = 0; mi < 4; ++mi)
                    #pragma unroll
                    for (int ni = 0; ni < 4; ++ni)
                        acc[mi][ni] = __builtin_amdgcn_mfma_f32_16x16x32_bf16(
                            af[mi], bfv[ni], acc[mi][ni], 0, 0, 0);
            }
        }
    }

    const size_t zc = (size_t)z * sC;
    const int cr = (l >> 4) << 2;
    const int cc = l & 15;
    #pragma unroll
    for (int mi = 0; mi < 4; ++mi) {
        #pragma unroll
        for (int r = 0; r < 4; ++r) {
            const int m = m0 + wr * 64 + mi * 16 + cr + r;
            const float bm = (BIAS == 1) ? bias[m] : 0.0f;
            #pragma unroll
            for (int ni = 0; ni < 4; ++ni) {
                const int n = n0 + wc * 64 + ni * 16 + cc;
                float v = acc[mi][ni][r] + bm + ((BIAS == 2) ? bias[n] : 0.0f);
                const size_t idx = zc + (size_t)m * NDIM + n;
                if (EPI == 0) {
                    ((float*)c0v)[idx] = v;
                } else if (EPI == 1) {
                    ((unsigned short*)c0v)[idx] = f2bf(v);
                } else {
                    const unsigned short h = f2bf(v);
                    ((unsigned short*)c0v)[idx] = h;
                    ((unsigned short*)c1v)[idx] = f2bf(v - bf2f(h));
                }
            }
        }
    }
}

// ---------------------------------------------------------------------------
// row softmax: fp32 in, bf16 out; one 256-thread block per 512-elem row
__global__ __launch_bounds__(256) void softmax_bf16(
    const float* __restrict__ E, unsigned short* __restrict__ A)
{
    __shared__ float red[256];
    const float* p = E + (size_t)blockIdx.x * NDIM;
    unsigned short* q = A + (size_t)blockIdx.x * NDIM;
    const int t = threadIdx.x;

    const float2 v = *(const float2*)(p + 2 * t);
    red[t] = fmaxf(v.x, v.y);
    __syncthreads();
    for (int s = 128; s > 0; s >>= 1) {
        if (t < s) red[t] = fmaxf(red[t], red[t + s]);
        __syncthreads();
    }
    const float mx = red[0];
    __syncthreads();

    const float ex = __expf(v.x - mx), ey = __expf(v.y - mx);
    red[t] = ex + ey;
    __syncthreads();
    for (int s = 128; s > 0; s >>= 1) {
        if (t < s) red[t] += red[t + s];
        __syncthreads();
    }
    const float inv = 1.0f / red[0];
    us2 o; o.x = f2bf(ex * inv); o.y = f2bf(ey * inv);
    *(us2*)(q + 2 * t) = o;
}

// ---------------------------------------------------------------------------
// fp32 -> bf16 hi (+ optional lo = bf16(v - hi)), float4-vectorized
template<bool LO>
__global__ __launch_bounds__(256) void split_to_bf16(
    const float* __restrict__ src,
    unsigned short* __restrict__ hi, unsigned short* __restrict__ lo, int n4)
{
    const int i = blockIdx.x * 256 + threadIdx.x;
    if (i >= n4) return;
    const float4 v = ((const float4*)src)[i];
    us4 h;
    h.x = f2bf(v.x); h.y = f2bf(v.y); h.z = f2bf(v.z); h.w = f2bf(v.w);
    ((us4*)hi)[i] = h;
    if (LO) {
        us4 g;
        g.x = f2bf(v.x - bf2f(h.x)); g.y = f2bf(v.y - bf2f(h.y));
        g.z = f2bf(v.z - bf2f(h.z)); g.w = f2bf(v.w - bf2f(h.w));
        ((us4*)lo)[i] = g;
    }
}

// ---------------------------------------------------------------------------
extern "C" void kernel_launch(void* const* d_in, const int* in_sizes, int n_in,
                              void* d_out, int out_size, void* d_ws, size_t ws_size,
                              hipStream_t stream)
{
    const float* x  = (const float*)d_in[0];
    const float* Wq = (const float*)d_in[1];
    const float* bq = (const float*)d_in[2];
    const float* Wk = (const float*)d_in[3];
    const float* bk = (const float*)d_in[4];
    const float* Wv = (const float*)d_in[5];
    const float* bv = (const float*)d_in[6];
    float* out = (float*)d_out;

    // ws budget in u16-units of SD: 6 weight units + 10*c per-chunk units
    long units = (long)(ws_size / (2 * SD));
    long cl = (units - 6) / 10;
    if (cl < 1) cl = 1;
    int c = 1;
    while (c * 2 <= cl && c < 128) c *= 2;     // largest pow2 <= cl, <= 128
    const bool use8 = (c >= 64);               // 8-phase needs grid >= 256 blk
    if (!use8 && c > 32) c = 32;

    unsigned short* p = (unsigned short*)d_ws;
    auto take = [&](size_t elems) { unsigned short* r = p; p += elems; return r; };
    unsigned short* WqH = take(SD);
    unsigned short* WqL = take(SD);
    unsigned short* WkH = take(SD);
    unsigned short* WkL = take(SD);
    unsigned short* WvH = take(SD);
    unsigned short* xH  = take((size_t)c * SD);
    unsigned short* xL  = take((size_t)c * SD);
    unsigned short* QH  = take((size_t)c * SD);
    unsigned short* QL  = take((size_t)c * SD);
    unsigned short* KH  = take((size_t)c * SD);
    unsigned short* KL  = take((size_t)c * SD);
    unsigned short* Vb  = take((size_t)c * SD);
    unsigned short* Ab  = take((size_t)c * SD);
    float* Ew = (float*)p;   // c*SD fp32

    const int n4w = (int)(SD / 4);
    split_to_bf16<true ><<<dim3((n4w + 255) / 256), dim3(256), 0, stream>>>(Wq, WqH, WqL, n4w);
    split_to_bf16<true ><<<dim3((n4w + 255) / 256), dim3(256), 0, stream>>>(Wk, WkH, WkL, n4w);
    split_to_bf16<false><<<dim3((n4w + 255) / 256), dim3(256), 0, stream>>>(Wv, WvH, nullptr, n4w);

    for (int b0 = 0; b0 < NBATCH; b0 += c) {
        const int cb = (NBATCH - b0 < c) ? (NBATCH - b0) : c;
        const int n4 = (int)((size_t)cb * SD / 4);
        split_to_bf16<true><<<dim3((n4 + 255) / 256), dim3(256), 0, stream>>>(
            x + (size_t)b0 * SD, xH, xL, n4);

        if (use8) {
            const dim3 g(4 * cb), blk(512);
            gemm8_nt<3, 2, 1><<<g, blk, 0, stream>>>(
                WqH, WqL, WqH, 0,  xH, xH, xL, (long)SD,  QH, QL, (long)SD, bq);
            gemm8_nt<3, 2, 2><<<g, blk, 0, stream>>>(
                xH, xL, xH, (long)SD,  WkH, WkH, WkL, 0,  KH, KL, (long)SD, bk);
            gemm8_nt<1, 1, 2><<<g, blk, 0, stream>>>(
                xH, nullptr, nullptr, (long)SD,  WvH, nullptr, nullptr, 0,  Vb, nullptr, (long)SD, bv);
            gemm8_nt<3, 0, 0><<<g, blk, 0, stream>>>(
                QH, QL, QH, (long)SD,  KH, KH, KL, (long)SD,  Ew, nullptr, (long)SD, nullptr);
            softmax_bf16<<<dim3(cb * NDIM), dim3(256), 0, stream>>>(Ew, Ab);
            gemm8_nt<1, 0, 0><<<g, blk, 0, stream>>>(
                Vb, nullptr, nullptr, (long)SD,  Ab, nullptr, nullptr, (long)SD,
                out + (size_t)b0 * SD, nullptr, (long)SD, nullptr);
        } else {
            const dim3 g(4, 4, cb), blk(256);
            gemm_bf16_nt<3, 2, 1><<<g, blk, 0, stream>>>(
                WqH, WqL, WqH, 0,  xH, xH, xL, (long)SD,  QH, QL, (long)SD, bq);
            gemm_bf16_nt<3, 2, 2><<<g, blk, 0, stream>>>(
                xH, xL, xH, (long)SD,  WkH, WkH, WkL, 0,  KH, KL, (long)SD, bk);
            gemm_bf16_nt<1, 1, 2><<<g, blk, 0, stream>>>(
                xH, nullptr, nullptr, (long)SD,  WvH, nullptr, nullptr, 0,  Vb, nullptr, (long)SD, bv);
            gemm_bf16_nt<3, 0, 0><<<g, blk, 0, stream>>>(
                QH, QL, QH, (long)SD,  KH, KH, KL, (long)SD,  Ew, nullptr, (long)SD, nullptr);
            softmax_bf16<<<dim3(cb * NDIM), dim3(256), 0, stream>>>(Ew, Ab);
            gemm_bf16_nt<1, 0, 0><<<g, blk, 0, stream>>>(
                Vb, nullptr, nullptr, (long)SD,  Ab, nullptr, nullptr, (long)SD,
                out + (size_t)b0 * SD, nullptr, (long)SD, nullptr);
        }
    }
}